// Round 8
// baseline (1372.427 us; speedup 1.0000x reference)
//
#include <hip/hip_runtime.h>

#define L_ 6
#define E_ 768
#define H_ 12
#define T_ 1024
#define B_ 4
#define V_ 256
#define M_ (B_*T_)      // 4096 tokens
#define E4_ (4*E_)      // 3072
#define QKVN (3*E_)     // 2304
#define NZL 4           // split-K slices for lm_head

typedef __bf16 bf16;
typedef __bf16 bf16x8 __attribute__((ext_vector_type(8)));
typedef __bf16 bf16x4 __attribute__((ext_vector_type(4)));
typedef float f32x4 __attribute__((ext_vector_type(4)));

#define GF_GELU     1
#define GF_BIAS_EXT 16
#define GF_PART     32   // write fp32 partials at outp + z*M*N
#define GF_RESID    64   // fp32 RMW: outp[idx] += acc + bias (sole writer per idx)

// dual-mode scalar load of a "float" input that may be fp32 or bf16
__device__ __forceinline__ float ldf(const void* p, size_t i, int f32m) {
    return f32m ? ((const float*)p)[i] : (float)((const bf16*)p)[i];
}

// async global->LDS, 16B per lane; LDS dest = wave-uniform base + lane*16 (m97/m104)
__device__ __forceinline__ void async_cp16(const void* g, void* l) {
    __builtin_amdgcn_global_load_lds(
        (__attribute__((address_space(1))) void*)g,
        (__attribute__((address_space(3))) void*)l, 16, 0, 0);
}

// raw v_exp_f32 (input in log2 domain); avoids ocml expf's mul+fixup
__device__ __forceinline__ float exp2_hw(float x) {
    float r; asm("v_exp_f32 %0, %1" : "=v"(r) : "v"(x)); return r;
}

// exact-GELU via A&S 7.1.26 erf (|err| < 1.5e-7, well under bf16 rounding)
__device__ __forceinline__ float gelu_f(float v) {
    float ax = fabsf(v) * 0.70710678118654752f;
    float t  = 1.f / (1.f + 0.3275911f * ax);
    float p  = t*(0.254829592f + t*(-0.284496736f + t*(1.421413741f
             + t*(-1.453152027f + t*1.061405429f))));
    float e  = exp2_hw(-1.4426950408889634f * ax * ax);
    float er = __builtin_copysignf(1.f - p * e, v);
    return 0.5f * v * (1.f + er);
}

// XCD-affinity block decode (flat grid, M/128 == 32 rows, 8 XCDs x 4 panels):
// XCD j (= f&7 under round-robin dispatch) owns bm in {4j..4j+3}; its 4 A-panels
// stay L2-resident across all bn (verified: W2 FETCH 109 -> 37 MB, r7).
__device__ __forceinline__ void xcd_decode(int f, int& bm, int& bn) {
    int s = f >> 3;
    bm = ((f & 7) << 2) + (s & 3);
    bn = s >> 2;
}

// ---------------- dtype probe: dm[0]=inputs-are-fp32, dm[1]=idx-is-int64 --------
__global__ __launch_bounds__(256) void k_probe(const void* __restrict__ tok,
    const void* __restrict__ idxp, int* __restrict__ dm)
{
    __shared__ int sc1, sc2;
    if (threadIdx.x == 0) { sc1 = 0; sc2 = 0; }
    __syncthreads();
    const bf16* tb = (const bf16*)tok;
    int c1 = 0;
    for (int i = threadIdx.x; i < 4096; i += 256) {
        float v = (float)tb[2 * i];
        if (!(fabsf(v) < 100.f)) c1++;          // NaN lands here too
    }
    const int* ip = (const int*)idxp;
    int c2 = 0;
    for (int i = threadIdx.x; i < 1024; i += 256)
        if (ip[2 * i + 1] != 0) c2++;
    atomicAdd(&sc1, c1);
    atomicAdd(&sc2, c2);
    __syncthreads();
    if (threadIdx.x == 0) { dm[0] = (sc1 > 400) ? 1 : 0; dm[1] = (sc2 < 100) ? 1 : 0; }
}

// ---------------- embedding: x = tok_emb[idx] + pos_emb ----------------
__global__ __launch_bounds__(256) void k_embed(const void* __restrict__ idxp,
    const void* __restrict__ tok, const void* __restrict__ pos,
    float* __restrict__ x, const int* __restrict__ dm)
{
    int f32m = dm[0], i64m = dm[1];
    int bt = blockIdx.x;
    int t  = bt & (T_ - 1);
    int id = i64m ? ((const int*)idxp)[2 * bt] : ((const int*)idxp)[bt]; // LE low word
    float* xo = x + (size_t)bt * E_;
    for (int e = threadIdx.x; e < E_; e += 256)
        xo[e] = ldf(tok, (size_t)id * E_ + e, f32m) + ldf(pos, (size_t)t * E_ + e, f32m);
}

// ---------------- layernorm: fp32 x -> bf16 out (w,b external, +elem offset) ----
__global__ __launch_bounds__(256) void k_ln(const float* __restrict__ x,
    const void* __restrict__ w, const void* __restrict__ b, size_t wboff,
    bf16* __restrict__ out, const int* __restrict__ dm)
{
    int f32m = dm[0];
    int row = blockIdx.x;
    int tid = threadIdx.x;
    const float* xr = x + (size_t)row * E_;
    float v0 = xr[tid], v1 = xr[tid + 256], v2 = xr[tid + 512];
    float s  = v0 + v1 + v2;
    float s2 = v0*v0 + v1*v1 + v2*v2;
    for (int off = 32; off; off >>= 1) {
        s  += __shfl_xor(s,  off);
        s2 += __shfl_xor(s2, off);
    }
    __shared__ float ls[4], ls2[4];
    int wave = tid >> 6;
    if ((tid & 63) == 0) { ls[wave] = s; ls2[wave] = s2; }
    __syncthreads();
    s  = ls[0] + ls[1] + ls[2] + ls[3];
    s2 = ls2[0] + ls2[1] + ls2[2] + ls2[3];
    float mu  = s * (1.0f / E_);
    float var = s2 * (1.0f / E_) - mu * mu;
    float rs  = rsqrtf(var + 1e-5f);
    bf16* o = out + (size_t)row * E_;
    o[tid]       = (bf16)(((v0 - mu) * rs) * ldf(w, wboff + tid,       f32m) + ldf(b, wboff + tid,       f32m));
    o[tid + 256] = (bf16)(((v1 - mu) * rs) * ldf(w, wboff + tid + 256, f32m) + ldf(b, wboff + tid + 256, f32m));
    o[tid + 512] = (bf16)(((v2 - mu) * rs) * ldf(w, wboff + tid + 512, f32m) + ldf(b, wboff + tid + 512, f32m));
}

// ------- batched transpose: z-th slice of [Z,R,C] external -> bf16 [Z,C,R] ------
__global__ __launch_bounds__(256) void k_transposeZ(const void* __restrict__ in,
    size_t inoff, size_t zin, bf16* __restrict__ out, size_t zout,
    int R, int C, const int* __restrict__ dm)
{
    int f32m = dm[0];
    __shared__ bf16 tile[32][33];
    size_t io = inoff + (size_t)blockIdx.z * zin;
    bf16* o = out + (size_t)blockIdx.z * zout;
    int r0 = blockIdx.x * 32, c0 = blockIdx.y * 32;
    int tx = threadIdx.x & 31, ty = threadIdx.x >> 5;   // 32 x 8
    #pragma unroll
    for (int i = 0; i < 4; i++)
        tile[ty + 8*i][tx] = (bf16)ldf(in, io + (size_t)(r0 + ty + 8*i) * C + (c0 + tx), f32m);
    __syncthreads();
    #pragma unroll
    for (int i = 0; i < 4; i++)
        o[(size_t)(c0 + ty + 8*i) * R + (r0 + tx)] = tile[tx][ty + 8*i];
}

// Wq/Wk/Wv all-layer transpose: z = l*3 + which -> out[l][which][E][E]
__global__ __launch_bounds__(256) void k_transpose3L(const void* __restrict__ a,
    const void* __restrict__ b, const void* __restrict__ c,
    bf16* __restrict__ out, const int* __restrict__ dm)
{
    int f32m = dm[0];
    int z = blockIdx.z, l = z / 3, wsel = z - 3 * l;
    const void* in = (wsel == 0) ? a : ((wsel == 1) ? b : c);
    size_t io = (size_t)l * E_ * E_;
    bf16* o = out + (size_t)z * E_ * E_;
    __shared__ bf16 tile[32][33];
    int r0 = blockIdx.x * 32, c0 = blockIdx.y * 32;
    int tx = threadIdx.x & 31, ty = threadIdx.x >> 5;
    #pragma unroll
    for (int i = 0; i < 4; i++)
        tile[ty + 8*i][tx] = (bf16)ldf(in, io + (size_t)(r0 + ty + 8*i) * E_ + (c0 + tx), f32m);
    __syncthreads();
    #pragma unroll
    for (int i = 0; i < 4; i++)
        o[(size_t)(c0 + ty + 8*i) * E_ + (r0 + tx)] = tile[tx][ty + 8*i];
}

// ------- all-layer QKV bias concat: out[l][QKVN] --------------------------------
__global__ __launch_bounds__(256) void k_cat3L(const void* __restrict__ a,
    const void* __restrict__ b, const void* __restrict__ c,
    bf16* __restrict__ o, const int* __restrict__ dm)
{
    int f32m = dm[0];
    int i = blockIdx.x * 256 + threadIdx.x;   // grid covers L_*QKVN exactly
    int l = i / QKVN, j = i - l * QKVN;
    float v = (j < E_) ? ldf(a, (size_t)l * E_ + j, f32m)
            : ((j < 2*E_) ? ldf(b, (size_t)l * E_ + j - E_, f32m)
                          : ldf(c, (size_t)l * E_ + j - 2*E_, f32m));
    o[i] = (bf16)v;
}

// ---------------- reduce NZL fp32 lm_head partials -> output dtype --------------
__global__ __launch_bounds__(256) void k_cast_red(const float* __restrict__ in,
    void* __restrict__ out, const int* __restrict__ dm)
{
    const size_t S = (size_t)M_ * V_ / 4;     // f32x4 stride per z-slice
    size_t i = (size_t)blockIdx.x * 256 + threadIdx.x;
    const f32x4* p = (const f32x4*)in;
    f32x4 v = p[i];
    v += p[S + i];
    v += p[2*S + i];
    v += p[3*S + i];
    if (dm[0]) {
        ((f32x4*)out)[i] = v;
    } else {
        bf16x4 o;
        #pragma unroll
        for (int j = 0; j < 4; j++) o[j] = (bf16)v[j];
        ((bf16x4*)out)[i] = o;
    }
}

// ---------------- GEMM 128x128, single-buffered (round-4 verified 40.6 us) ------
// Flat 1-D grid, XCD-affinity decode. Double-buffering measured 74 us (64 KB LDS
// -> 2 blocks/CU residency loss, m132 lesson). At 2.25-3 blocks/CU the implicit
// wave overlap covers load latency (m131-140 regime) — leave single-buffered.
__global__ __launch_bounds__(256) void k_gemm(const bf16* __restrict__ A,
    const bf16* __restrict__ BT, const void* __restrict__ bias, size_t boff,
    void* __restrict__ outp, int M, int N, int K, int flags, const int* __restrict__ dm)
{
    int f32m = dm[0];
    __shared__ __attribute__((aligned(16))) bf16 As[128 * 64];
    __shared__ __attribute__((aligned(16))) bf16 Bs[128 * 64];
    int tid = threadIdx.x;
    int bmq, bnq;
    xcd_decode(blockIdx.x, bmq, bnq);
    int bn0 = bnq * 128, bm0 = bmq * 128;
    int wave = tid >> 6, lane = tid & 63, quad = lane >> 4, l16 = lane & 15;
    int wr = wave >> 1, wc = wave & 1;

    int st_col = 8 * ((lane & 7) ^ (lane >> 3));
    int st_row_base = wave * 32 + (lane >> 3);      // + i*8

    f32x4 acc[4][4];
    #pragma unroll
    for (int i = 0; i < 4; i++)
        #pragma unroll
        for (int j = 0; j < 4; j++)
            acc[i][j] = (f32x4){0.f, 0.f, 0.f, 0.f};

    int sw = l16 & 7;                               // read-side swizzle key
    for (int k0 = 0; k0 < K; k0 += 64) {
        #pragma unroll
        for (int i = 0; i < 4; i++) {
            int row = st_row_base + i * 8;
            const bf16* ga = A  + (size_t)(bm0 + row) * K + k0 + st_col;
            const bf16* gb = BT + (size_t)(bn0 + row) * K + k0 + st_col;
            bf16* la = As + (size_t)(wave * 256 + i * 64) * 8;
            bf16* lb = Bs + (size_t)(wave * 256 + i * 64) * 8;
            async_cp16(ga, la);
            async_cp16(gb, lb);
        }
        __syncthreads();
        #pragma unroll
        for (int ks = 0; ks < 2; ks++) {
            bf16x8 af[4], bfr[4];
            int kgs = (4*ks + quad) ^ sw;
            #pragma unroll
            for (int mi = 0; mi < 4; mi++)
                af[mi] = *(const bf16x8*)&As[(wr*64 + mi*16 + l16)*64 + kgs*8];
            #pragma unroll
            for (int ni = 0; ni < 4; ni++)
                bfr[ni] = *(const bf16x8*)&Bs[(wc*64 + ni*16 + l16)*64 + kgs*8];
            #pragma unroll
            for (int mi = 0; mi < 4; mi++)
                #pragma unroll
                for (int ni = 0; ni < 4; ni++)
                    acc[mi][ni] = __builtin_amdgcn_mfma_f32_16x16x32_bf16(af[mi], bfr[ni], acc[mi][ni], 0, 0, 0);
        }
        __syncthreads();
    }

    // epilogue: D row = base + 4*quad + reg, col = base + l16 (m89-verified)
    #pragma unroll
    for (int mi = 0; mi < 4; mi++) {
        #pragma unroll
        for (int ni = 0; ni < 4; ni++) {
            int col = bn0 + wc*64 + ni*16 + l16;
            float bv = 0.f;
            if (bias)
                bv = (flags & GF_BIAS_EXT) ? ldf(bias, boff + col, f32m)
                                           : (float)((const bf16*)bias)[col];
            #pragma unroll
            for (int r = 0; r < 4; r++) {
                int row = bm0 + wr*64 + mi*16 + quad*4 + r;
                float val = acc[mi][ni][r] + bv;
                if (flags & GF_GELU) val = gelu_f(val);
                size_t oidx = (size_t)row * N + col;
                ((bf16*)outp)[oidx] = (bf16)val;
            }
        }
    }
}

// ---------------- GEMM 128x64, double-buffered + COUNTED vmcnt (T4) -------------
// At 1.5 blocks/CU the __syncthreads full-drain (vmcnt(0)) serialized every
// K-step: MFMA + full load latency back-to-back (r7: FETCH fixed to 37 MB but
// dur stuck at 54 us, HBM 0.93 TB/s -> latency-bound). Counted scheme: after
// issuing the t+1 prefetch (6 loads), wait vmcnt(6) = only the CURRENT buffer's
// 6 oldest loads; raw s_barrier publishes them across waves; MFMA runs with the
// next tile's loads still in flight (m218: counted-vs-drain +38-73%).
__global__ __launch_bounds__(256) void k_gemm64(const bf16* __restrict__ A,
    const bf16* __restrict__ BT, const void* __restrict__ bias, size_t boff,
    void* __restrict__ outp, int M, int N, int K, int flags, const int* __restrict__ dm)
{
    int f32m = dm[0];
    __shared__ __attribute__((aligned(16))) bf16 As[2][128 * 64];
    __shared__ __attribute__((aligned(16))) bf16 Bs[2][64 * 64];
    int tid = threadIdx.x;
    int bmq, bnq;
    xcd_decode(blockIdx.x, bmq, bnq);
    int bn0 = bnq * 64, bm0 = bmq * 128;
    int kz = blockIdx.z;
    int Ks = K / gridDim.z;
    int kbeg = kz * Ks;
    int wave = tid >> 6, lane = tid & 63, quad = lane >> 4, l16 = lane & 15;
    int wr = wave >> 1, wc = wave & 1;

    int st_col = 8 * ((lane & 7) ^ (lane >> 3));
    int lrow = lane >> 3;

    f32x4 acc[4][2];
    #pragma unroll
    for (int i = 0; i < 4; i++)
        #pragma unroll
        for (int j = 0; j < 2; j++)
            acc[i][j] = (f32x4){0.f, 0.f, 0.f, 0.f};

    auto stage = [&](int buf, int k0) {              // 6 global_load_lds per wave
        #pragma unroll
        for (int i = 0; i < 4; i++) {       // A: 128 rows
            int row = wave * 32 + i * 8 + lrow;
            async_cp16(A + (size_t)(bm0 + row) * K + k0 + st_col,
                       &As[buf][(size_t)(wave * 32 + i * 8) * 64]);
        }
        #pragma unroll
        for (int i = 0; i < 2; i++) {       // B: 64 rows
            int row = wave * 16 + i * 8 + lrow;
            async_cp16(BT + (size_t)(bn0 + row) * K + k0 + st_col,
                       &Bs[buf][(size_t)(wave * 16 + i * 8) * 64]);
        }
    };

    int nt = Ks / 64;
    int sw = l16 & 7;
    stage(0, kbeg);
    for (int t = 0; t < nt; ++t) {
        int cur = t & 1;
        if (t + 1 < nt) {
            stage(cur ^ 1, kbeg + (t + 1) * 64);     // 12 outstanding
            asm volatile("s_waitcnt vmcnt(6)" ::: "memory");   // cur's 6 landed
        } else {
            asm volatile("s_waitcnt vmcnt(0)" ::: "memory");
        }
        __builtin_amdgcn_s_barrier();                // publish cur across waves
        __builtin_amdgcn_sched_barrier(0);           // pin: no ds_read hoisting
        #pragma unroll
        for (int ks = 0; ks < 2; ks++) {
            int kgs = (4*ks + quad) ^ sw;
            bf16x8 af[4], bfr[2];
            #pragma unroll
            for (int mi = 0; mi < 4; mi++)
                af[mi] = *(const bf16x8*)&As[cur][(wr*64 + mi*16 + l16)*64 + kgs*8];
            #pragma unroll
            for (int ni = 0; ni < 2; ni++)
                bfr[ni] = *(const bf16x8*)&Bs[cur][(wc*32 + ni*16 + l16)*64 + kgs*8];
            #pragma unroll
            for (int mi = 0; mi < 4; mi++)
                #pragma unroll
                for (int ni = 0; ni < 2; ni++)
                    acc[mi][ni] = __builtin_amdgcn_mfma_f32_16x16x32_bf16(af[mi], bfr[ni], acc[mi][ni], 0, 0, 0);
        }
        asm volatile("s_waitcnt lgkmcnt(0)" ::: "memory");  // cur reads done
        __builtin_amdgcn_s_barrier();                // safe to overwrite cur next iter
    }

    float* pout = (float*)outp + (size_t)kz * M * N;   // partial slice (GF_PART)
    #pragma unroll
    for (int mi = 0; mi < 4; mi++) {
        #pragma unroll
        for (int ni = 0; ni < 2; ni++) {
            int col = bn0 + wc*32 + ni*16 + l16;
            float bv = 0.f;
            if (bias)
                bv = (flags & GF_BIAS_EXT) ? ldf(bias, boff + col, f32m)
                                           : (float)((const bf16*)bias)[col];
            #pragma unroll
            for (int r = 0; r < 4; r++) {
                int row = bm0 + wr*64 + mi*16 + quad*4 + r;
                float val = acc[mi][ni][r] + bv;
                size_t oidx = (size_t)row * N + col;
                if (flags & GF_RESID) {
                    float* xo = (float*)outp;
                    xo[oidx] += val;                 // sole writer: plain RMW
                } else if (flags & GF_PART) {
                    pout[oidx] = val;
                } else {
                    ((bf16*)outp)[oidx] = (bf16)val;
                }
            }
        }
    }
}

// ---------------- flash attention (1 strip/block, async 2-phase pipeline) --------
__device__ __forceinline__ void attn_qk_softmax2(
    const bf16x8 qf[2], f32x4 OT[4], float& m_ln, float& l_ln,
    const bf16* __restrict__ Kbuf, bf16 (*Ps)[72],
    int wave, int quad, int l16, int s0, int qt0, bool diag)
{
    f32x4 S[4];
    #pragma unroll
    for (int i = 0; i < 4; i++) S[i] = (f32x4){0.f, 0.f, 0.f, 0.f};
    #pragma unroll
    for (int ks = 0; ks < 2; ks++)
        #pragma unroll
        for (int ni = 0; ni < 4; ni++) {
            int kg = (ks*4 + quad) ^ (l16 & 7);
            bf16x8 kf = *(const bf16x8*)&Kbuf[(ni*16 + l16)*64 + kg*8];
            S[ni] = __builtin_amdgcn_mfma_f32_16x16x32_bf16(kf, qf[ks], S[ni], 0, 0, 0);
        }
    const float SC = 0.18033688011112042f;   // 0.125 * log2(e): softmax in base-2
    if (diag) {
        int qr = qt0 + wave*16 + l16;
        #pragma unroll
        for (int ni = 0; ni < 4; ni++)
            #pragma unroll
            for (int r = 0; r < 4; r++) {
                int scol = s0 + ni*16 + quad*4 + r;
                S[ni][r] = (scol > qr) ? -1e30f : S[ni][r] * SC;
            }
    } else {
        #pragma unroll
        for (int ni = 0; ni < 4; ni++)
            #pragma unroll
            for (int r = 0; r < 4; r++) S[ni][r] *= SC;
    }
    float tn[4];
    #pragma unroll
    for (int ni = 0; ni < 4; ni++)
        tn[ni] = fmaxf(fmaxf(S[ni][0], S[ni][1]), fmaxf(S[ni][2], S[ni][3]));
    float tm = fmaxf(fmaxf(tn[0], tn[1]), fmaxf(tn[2], tn[3]));
    tm = fmaxf(tm, __shfl_xor(tm, 16));
    tm = fmaxf(tm, __shfl_xor(tm, 32));
    float mnew = fmaxf(m_ln, tm);
    float alpha = exp2_hw(m_ln - mnew);
    m_ln = mnew;
    float rsum = 0.f;
    bf16x4 pk[4];
    #pragma unroll
    for (int ni = 0; ni < 4; ni++)
        #pragma unroll
        for (int r = 0; r < 4; r++) {
            float p = exp2_hw(S[ni][r] - mnew);
            rsum += p;
            pk[ni][r] = (bf16)p;
        }
    rsum += __shfl_xor(rsum, 16);
    rsum += __shfl_xor(rsum, 32);
    l_ln = l_ln * alpha + rsum;
    #pragma unroll
    for (int ni = 0; ni < 4; ni++)
        #pragma unroll
        for (int r = 0; r < 4; r++) OT[ni][r] *= alpha;        // lane-local rescale
    #pragma unroll
    for (int ni = 0; ni < 4; ni++)
        *(bf16x4*)&Ps[wave*16 + l16][ni*16 + quad*4] = pk[ni]; // wave-private rows
}

__device__ __forceinline__ void attn_pv(
    f32x4 OT[4], const bf16 (*Ps)[72], const bf16 (*Vt)[72],
    int wave, int quad, int l16)
{
    #pragma unroll
    for (int ks = 0; ks < 2; ks++) {
        bf16x8 pf = *(const bf16x8*)&Ps[wave*16 + l16][ks*32 + quad*8];
        #pragma unroll
        for (int ni = 0; ni < 4; ni++) {
            bf16x8 vf = *(const bf16x8*)&Vt[ni*16 + l16][ks*32 + quad*8];
            OT[ni] = __builtin_amdgcn_mfma_f32_16x16x32_bf16(vf, pf, OT[ni], 0, 0, 0);
        }
    }
}

__global__ __launch_bounds__(256) void k_attn(const bf16* __restrict__ qkv, bf16* __restrict__ y)
{
    int x = blockIdx.x;               // q-strip 0..15
    int qt = x * 64;
    int h = blockIdx.y, b = blockIdx.z;
    int tid = threadIdx.x, wave = tid >> 6, lane = tid & 63, quad = lane >> 4, l16 = lane & 15;

    const bf16* qb = qkv + (size_t)b * T_ * QKVN + h * 64;
    const bf16* kb = qb + E_;
    const bf16* vb = qb + 2 * E_;

    __shared__ __attribute__((aligned(16))) bf16 Kbuf[64 * 64];   // async dest, swizzled
    __shared__ __attribute__((aligned(16))) bf16 Vbuf[64 * 64];   // async dest, swizzled
    __shared__ __attribute__((aligned(16))) bf16 Vt[64][72];      // Vt[d][s]
    __shared__ __attribute__((aligned(16))) bf16 Ps[64][72];      // wave-private P rows

    // staging geometry: 8 lanes x 16B per row; XOR swizzle on SOURCE col (m173)
    int srow = tid >> 3;                               // 0..31 (+32 round 2)
    int scol = 8 * ((lane & 7) ^ (srow & 7));

    bf16x8 qf[2];
    {
        int qr = qt + wave * 16 + l16;
        #pragma unroll
        for (int ks = 0; ks < 2; ks++)
            qf[ks] = *(const bf16x8*)(qb + (size_t)qr * QKVN + ks*32 + quad*8);
    }

    f32x4 OT[4];
    #pragma unroll
    for (int i = 0; i < 4; i++) OT[i] = (f32x4){0.f,0.f,0.f,0.f};
    float m_ln = -3.0e38f, l_ln = 0.f;

    auto stage = [&](int s0) {
        #pragma unroll
        for (int i = 0; i < 2; i++) {
            int row = i * 32 + srow;
            const bf16* gk = kb + (size_t)(s0 + row) * QKVN + scol;
            const bf16* gv = vb + (size_t)(s0 + row) * QKVN + scol;
            bf16* lk = Kbuf + ((size_t)i * 32 + wave * 8) * 64;   // linear dest
            bf16* lv = Vbuf + ((size_t)i * 32 + wave * 8) * 64;
            async_cp16(gk, lk);
            async_cp16(gv, lv);
        }
    };

    stage(0);
    asm volatile("s_waitcnt vmcnt(0)" ::: "memory");
    __syncthreads();

    for (int st = 0; st <= x; st++) {
        int s0 = st * 64;
        // ---- phase 1: V transpose (Vbuf->Vt) overlapped with QK^T + softmax ----
        {
            int d = lane;
            int dg = d >> 3, de = d & 7;
            #pragma unroll
            for (int ii = 0; ii < 2; ii++) {
                int sb = wave * 2 + ii;                 // 0..7
                bf16x8 tv;
                #pragma unroll
                for (int j = 0; j < 8; j++)
                    tv[j] = Vbuf[(sb*8 + j) * 64 + ((dg ^ j) * 8) + de];
                *(bf16x8*)&Vt[d][sb * 8] = tv;
            }
        }
        attn_qk_softmax2(qf, OT, m_ln, l_ln, Kbuf, Ps, wave, quad, l16, s0, qt, st == x);
        __syncthreads();                  // Vt + Ps visible; Kbuf/Vbuf reads done
        // ---- phase 2: async stage(st+1) overlapped with PV ----
        if (st < x) stage(s0 + 64);
        attn_pv(OT, Ps, Vt, wave, quad, l16);
        asm volatile("s_waitcnt vmcnt(0)" ::: "memory");
        __syncthreads();                  // stage landed; Vt/Ps reads done
    }

    float inv = 1.f / l_ln;               // lane-local (q = w*16+l16)
    int qrow = qt + wave * 16 + l16;
    #pragma unroll
    for (int ni = 0; ni < 4; ni++) {
        bf16x4 ov;
        #pragma unroll
        for (int r = 0; r < 4; r++) ov[r] = (bf16)(OT[ni][r] * inv);
        *(bf16x4*)&y[(size_t)(b * T_ + qrow) * E_ + h*64 + ni*16 + quad*4] = ov;
    }
}

// ---------------- host-side orchestration ----------------
extern "C" void kernel_launch(void* const* d_in, const int* in_sizes, int n_in,
                              void* d_out, int out_size, void* d_ws, size_t ws_size,
                              hipStream_t stream)
{
    const void* idx     = d_in[0];
    const void* tok_emb = d_in[1];
    const void* pos_emb = d_in[2];
    const void* ln1_w   = d_in[3];
    const void* ln1_b   = d_in[4];
    const void* Wq      = d_in[5];
    const void* bq      = d_in[6];
    const void* Wk      = d_in[7];
    const void* bk      = d_in[8];
    const void* Wv      = d_in[9];
    const void* bv      = d_in[10];
    const void* Wp      = d_in[11];
    const void* bp      = d_in[12];
    const void* ln2_w   = d_in[13];
    const void* ln2_b   = d_in[14];
    const void* W1      = d_in[15];
    const void* b1      = d_in[16];
    const void* W2      = d_in[17];
    const void* b2      = d_in[18];
    const void* lnf_w   = d_in[19];
    const void* lnf_b   = d_in[20];
    const void* lm_head = d_in[21];

    char* base = (char*)d_ws;
    size_t off = 0;
    auto nxt = [&](size_t bytes) -> void* {
        void* p = base + off;
        off += (bytes + 255) & ~(size_t)255;
        return p;
    };
    int*   dm    = (int*)  nxt(256);                       // dtype-mode flags
    float* x     = (float*)nxt((size_t)M_ * E_ * 4);       // fp32 residual stream
    bf16*  h     = (bf16*) nxt((size_t)M_ * E_ * 2);       // LN output
    bf16*  qkv   = (bf16*) nxt((size_t)M_ * QKVN * 2);
    bf16*  yb    = (bf16*) nxt((size_t)M_ * E_ * 2);       // attention output
    bf16*  mbuf  = (bf16*) nxt((size_t)M_ * E4_ * 2);      // MLP intermediate
    bf16*  wqkvT = (bf16*) nxt((size_t)L_ * 3 * E_ * E_ * 2);  // all-layer W transposes
    bf16*  wpT   = (bf16*) nxt((size_t)L_ * E_ * E_ * 2);
    bf16*  w1T   = (bf16*) nxt((size_t)L_ * E_ * E4_ * 2);
    bf16*  w2T   = (bf16*) nxt((size_t)L_ * E4_ * E_ * 2);
    bf16*  lmhT  = (bf16*) nxt((size_t)V_ * E_ * 2);
    bf16*  bcat  = (bf16*) nxt((size_t)L_ * QKVN * 2);
    float* part  = (float*)nxt((size_t)NZL * M_ * V_ * 4); // lm_head split-K partials
    (void)ws_size; (void)in_sizes; (void)n_in; (void)out_size;

    k_probe<<<1, 256, 0, stream>>>(tok_emb, idx, dm);
    k_embed<<<M_, 256, 0, stream>>>(idx, tok_emb, pos_emb, x, dm);

    // all weight transposes + bias concat upfront (layer-static)
    k_transpose3L<<<dim3(E_/32, E_/32, 3*L_), 256, 0, stream>>>(Wq, Wk, Wv, wqkvT, dm);
    k_transposeZ<<<dim3(E_/32, E_/32, L_), 256, 0, stream>>>(Wp, 0, (size_t)E_*E_, wpT, (size_t)E_*E_, E_, E_, dm);
    k_transposeZ<<<dim3(E_/32, E4_/32, L_), 256, 0, stream>>>(W1, 0, (size_t)E_*E4_, w1T, (size_t)E_*E4_, E_, E4_, dm);
    k_transposeZ<<<dim3(E4_/32, E_/32, L_), 256, 0, stream>>>(W2, 0, (size_t)E_*E4_, w2T, (size_t)E_*E4_, E4_, E_, dm);
    k_transposeZ<<<dim3(E_/32, V_/32, 1), 256, 0, stream>>>(lm_head, 0, 0, lmhT, 0, E_, V_, dm);
    k_cat3L<<<(L_*QKVN)/256, 256, 0, stream>>>(bq, bk, bv, bcat, dm);

    // ln1 of layer 0
    k_ln<<<M_, 256, 0, stream>>>(x, ln1_w, ln1_b, 0, h, dm);

    for (int l = 0; l < L_; l++) {
        size_t voE  = (size_t)l * E_;          // element offset into [L,E]
        size_t voE4 = (size_t)l * E4_;         // element offset into [L,4E]

        // h == ln1_l(x) here; flat grids = ncol_blocks * 32 (XCD-affinity decode)
        k_gemm<<<dim3((QKVN/128) * (M_/128)), 256, 0, stream>>>(h, wqkvT + (size_t)l*3*E_*E_,
            bcat + (size_t)l*QKVN, 0, qkv, M_, QKVN, E_, 0, dm);

        k_attn<<<dim3(16, H_, B_), 256, 0, stream>>>(qkv, yb);

        // proj: full-K BN=64, residual-fused epilogue (x += yb@Wp^T + bp)
        k_gemm64<<<dim3((E_/64) * (M_/128)), 256, 0, stream>>>(yb, wpT + (size_t)l*E_*E_,
            bp, voE, x, M_, E_, E_, GF_RESID | GF_BIAS_EXT, dm);
        k_ln<<<M_, 256, 0, stream>>>(x, ln2_w, ln2_b, voE, h, dm);

        k_gemm<<<dim3((E4_/128) * (M_/128)), 256, 0, stream>>>(h, w1T + (size_t)l*E_*E4_,
            b1, voE4, mbuf, M_, E4_, E_, GF_GELU | GF_BIAS_EXT, dm);

        // W2: full-K BN=64, residual-fused epilogue (x += mbuf@W2^T + b2)
        k_gemm64<<<dim3((E_/64) * (M_/128)), 256, 0, stream>>>(mbuf, w2T + (size_t)l*E_*E4_,
            b2, voE, x, M_, E_, E4_, GF_RESID | GF_BIAS_EXT, dm);
        if (l < L_ - 1)
            k_ln<<<M_, 256, 0, stream>>>(x, ln1_w, ln1_b, (size_t)(l+1) * E_, h, dm);
        else
            k_ln<<<M_, 256, 0, stream>>>(x, lnf_w, lnf_b, 0, h, dm);
    }

    // lm_head: split-K=4 (flat 128 blocks x z=4) partials -> fused reduce+cast
    k_gemm64<<<dim3((V_/64) * (M_/128), 1, NZL), 256, 0, stream>>>(h, lmhT, nullptr, 0,
        part, M_, V_, E_, GF_PART, dm);
    k_cast_red<<<(M_*V_)/1024, 256, 0, stream>>>(part, d_out, dm);
}

// Round 9
// 1265.523 us; speedup vs baseline: 1.0845x; 1.0845x over previous
//
#include <hip/hip_runtime.h>

#define L_ 6
#define E_ 768
#define H_ 12
#define T_ 1024
#define B_ 4
#define V_ 256
#define M_ (B_*T_)      // 4096 tokens
#define E4_ (4*E_)      // 3072
#define QKVN (3*E_)     // 2304
#define NZP 2           // split-K slices for N=768 GEMMs (proj/W2)
#define NZL 4           // split-K slices for lm_head

typedef __bf16 bf16;
typedef __bf16 bf16x8 __attribute__((ext_vector_type(8)));
typedef __bf16 bf16x4 __attribute__((ext_vector_type(4)));
typedef float f32x4 __attribute__((ext_vector_type(4)));

#define GF_GELU     1
#define GF_BIAS_EXT 16
#define GF_PART     32   // write fp32 partials at outp + z*M*N (no bias, no RMW)

// dual-mode scalar load of a "float" input that may be fp32 or bf16
__device__ __forceinline__ float ldf(const void* p, size_t i, int f32m) {
    return f32m ? ((const float*)p)[i] : (float)((const bf16*)p)[i];
}

// async global->LDS, 16B per lane; LDS dest = wave-uniform base + lane*16 (m97/m104)
__device__ __forceinline__ void async_cp16(const void* g, void* l) {
    __builtin_amdgcn_global_load_lds(
        (__attribute__((address_space(1))) void*)g,
        (__attribute__((address_space(3))) void*)l, 16, 0, 0);
}

// raw v_exp_f32 (input in log2 domain); avoids ocml expf's mul+fixup
__device__ __forceinline__ float exp2_hw(float x) {
    float r; asm("v_exp_f32 %0, %1" : "=v"(r) : "v"(x)); return r;
}

// exact-GELU via A&S 7.1.26 erf (|err| < 1.5e-7, well under bf16 rounding)
__device__ __forceinline__ float gelu_f(float v) {
    float ax = fabsf(v) * 0.70710678118654752f;
    float t  = 1.f / (1.f + 0.3275911f * ax);
    float p  = t*(0.254829592f + t*(-0.284496736f + t*(1.421413741f
             + t*(-1.453152027f + t*1.061405429f))));
    float e  = exp2_hw(-1.4426950408889634f * ax * ax);
    float er = __builtin_copysignf(1.f - p * e, v);
    return 0.5f * v * (1.f + er);
}

// XCD-affinity block decode (flat grid, M/128 == 32 rows, 8 XCDs x 4 panels):
// XCD j (= f&7 under round-robin dispatch) owns bm in {4j..4j+3}; its A-panels
// stay L2-resident across all bn (verified r7: W2 FETCH 109 -> 37 MB).
__device__ __forceinline__ void xcd_decode(int f, int& bm, int& bn) {
    int s = f >> 3;
    bm = ((f & 7) << 2) + (s & 3);
    bn = s >> 2;
}

// ---------------- dtype probe: dm[0]=inputs-are-fp32, dm[1]=idx-is-int64 --------
__global__ __launch_bounds__(256) void k_probe(const void* __restrict__ tok,
    const void* __restrict__ idxp, int* __restrict__ dm)
{
    __shared__ int sc1, sc2;
    if (threadIdx.x == 0) { sc1 = 0; sc2 = 0; }
    __syncthreads();
    const bf16* tb = (const bf16*)tok;
    int c1 = 0;
    for (int i = threadIdx.x; i < 4096; i += 256) {
        float v = (float)tb[2 * i];
        if (!(fabsf(v) < 100.f)) c1++;          // NaN lands here too
    }
    const int* ip = (const int*)idxp;
    int c2 = 0;
    for (int i = threadIdx.x; i < 1024; i += 256)
        if (ip[2 * i + 1] != 0) c2++;
    atomicAdd(&sc1, c1);
    atomicAdd(&sc2, c2);
    __syncthreads();
    if (threadIdx.x == 0) { dm[0] = (sc1 > 400) ? 1 : 0; dm[1] = (sc2 < 100) ? 1 : 0; }
}

// ---------------- embedding: x = tok_emb[idx] + pos_emb ----------------
__global__ __launch_bounds__(256) void k_embed(const void* __restrict__ idxp,
    const void* __restrict__ tok, const void* __restrict__ pos,
    float* __restrict__ x, const int* __restrict__ dm)
{
    int f32m = dm[0], i64m = dm[1];
    int bt = blockIdx.x;
    int t  = bt & (T_ - 1);
    int id = i64m ? ((const int*)idxp)[2 * bt] : ((const int*)idxp)[bt]; // LE low word
    float* xo = x + (size_t)bt * E_;
    for (int e = threadIdx.x; e < E_; e += 256)
        xo[e] = ldf(tok, (size_t)id * E_ + e, f32m) + ldf(pos, (size_t)t * E_ + e, f32m);
}

// ---------------- layernorm: fp32 x -> bf16 out (w,b external, +elem offset) ----
__global__ __launch_bounds__(256) void k_ln(const float* __restrict__ x,
    const void* __restrict__ w, const void* __restrict__ b, size_t wboff,
    bf16* __restrict__ out, const int* __restrict__ dm)
{
    int f32m = dm[0];
    int row = blockIdx.x;
    int tid = threadIdx.x;
    const float* xr = x + (size_t)row * E_;
    float v0 = xr[tid], v1 = xr[tid + 256], v2 = xr[tid + 512];
    float s  = v0 + v1 + v2;
    float s2 = v0*v0 + v1*v1 + v2*v2;
    for (int off = 32; off; off >>= 1) {
        s  += __shfl_xor(s,  off);
        s2 += __shfl_xor(s2, off);
    }
    __shared__ float ls[4], ls2[4];
    int wave = tid >> 6;
    if ((tid & 63) == 0) { ls[wave] = s; ls2[wave] = s2; }
    __syncthreads();
    s  = ls[0] + ls[1] + ls[2] + ls[3];
    s2 = ls2[0] + ls2[1] + ls2[2] + ls2[3];
    float mu  = s * (1.0f / E_);
    float var = s2 * (1.0f / E_) - mu * mu;
    float rs  = rsqrtf(var + 1e-5f);
    bf16* o = out + (size_t)row * E_;
    o[tid]       = (bf16)(((v0 - mu) * rs) * ldf(w, wboff + tid,       f32m) + ldf(b, wboff + tid,       f32m));
    o[tid + 256] = (bf16)(((v1 - mu) * rs) * ldf(w, wboff + tid + 256, f32m) + ldf(b, wboff + tid + 256, f32m));
    o[tid + 512] = (bf16)(((v2 - mu) * rs) * ldf(w, wboff + tid + 512, f32m) + ldf(b, wboff + tid + 512, f32m));
}

// ---------------- fused split-K reduce + residual + bias + layernorm ------------
// x[row] += sum_z part[z][row] + gbias ; out = LN(x[row]) with (w,b). NZP slices.
// (r4-verified structure: split-K=2 + this fusion beat full-K RESID because the
// 768-block grid keeps 3 blocks/CU — occupancy, not traffic, binds gemm64.)
__global__ __launch_bounds__(256) void k_red_ln(float* __restrict__ x,
    const float* __restrict__ part,
    const void* __restrict__ gb, size_t gboff,
    const void* __restrict__ w, const void* __restrict__ b, size_t wboff,
    bf16* __restrict__ out, const int* __restrict__ dm)
{
    const size_t PSTR = (size_t)M_ * E_;
    int f32m = dm[0];
    int row = blockIdx.x;
    int tid = threadIdx.x;
    float* xr = x + (size_t)row * E_;
    const float* pr = part + (size_t)row * E_;
    float v[3];
    #pragma unroll
    for (int j = 0; j < 3; j++) {
        int c = tid + j * 256;
        float acc = xr[c];
        #pragma unroll
        for (int z = 0; z < NZP; z++) acc += pr[(size_t)z * PSTR + c];
        acc += ldf(gb, gboff + c, f32m);
        v[j] = acc;
        xr[c] = acc;                      // updated residual stream
    }
    float s  = v[0] + v[1] + v[2];
    float s2 = v[0]*v[0] + v[1]*v[1] + v[2]*v[2];
    for (int off = 32; off; off >>= 1) {
        s  += __shfl_xor(s,  off);
        s2 += __shfl_xor(s2, off);
    }
    __shared__ float ls[4], ls2[4];
    int wave = tid >> 6;
    if ((tid & 63) == 0) { ls[wave] = s; ls2[wave] = s2; }
    __syncthreads();
    s  = ls[0] + ls[1] + ls[2] + ls[3];
    s2 = ls2[0] + ls2[1] + ls2[2] + ls2[3];
    float mu  = s * (1.0f / E_);
    float var = s2 * (1.0f / E_) - mu * mu;
    float rs  = rsqrtf(var + 1e-5f);
    bf16* o = out + (size_t)row * E_;
    #pragma unroll
    for (int j = 0; j < 3; j++) {
        int c = tid + j * 256;
        o[c] = (bf16)(((v[j] - mu) * rs) * ldf(w, wboff + c, f32m) + ldf(b, wboff + c, f32m));
    }
}

// ------- batched transpose: z-th slice of [Z,R,C] external -> bf16 [Z,C,R] ------
__global__ __launch_bounds__(256) void k_transposeZ(const void* __restrict__ in,
    size_t inoff, size_t zin, bf16* __restrict__ out, size_t zout,
    int R, int C, const int* __restrict__ dm)
{
    int f32m = dm[0];
    __shared__ bf16 tile[32][33];
    size_t io = inoff + (size_t)blockIdx.z * zin;
    bf16* o = out + (size_t)blockIdx.z * zout;
    int r0 = blockIdx.x * 32, c0 = blockIdx.y * 32;
    int tx = threadIdx.x & 31, ty = threadIdx.x >> 5;   // 32 x 8
    #pragma unroll
    for (int i = 0; i < 4; i++)
        tile[ty + 8*i][tx] = (bf16)ldf(in, io + (size_t)(r0 + ty + 8*i) * C + (c0 + tx), f32m);
    __syncthreads();
    #pragma unroll
    for (int i = 0; i < 4; i++)
        o[(size_t)(c0 + ty + 8*i) * R + (r0 + tx)] = tile[tx][ty + 8*i];
}

// Wq/Wk/Wv all-layer transpose: z = l*3 + which -> out[l][which][E][E]
__global__ __launch_bounds__(256) void k_transpose3L(const void* __restrict__ a,
    const void* __restrict__ b, const void* __restrict__ c,
    bf16* __restrict__ out, const int* __restrict__ dm)
{
    int f32m = dm[0];
    int z = blockIdx.z, l = z / 3, wsel = z - 3 * l;
    const void* in = (wsel == 0) ? a : ((wsel == 1) ? b : c);
    size_t io = (size_t)l * E_ * E_;
    bf16* o = out + (size_t)z * E_ * E_;
    __shared__ bf16 tile[32][33];
    int r0 = blockIdx.x * 32, c0 = blockIdx.y * 32;
    int tx = threadIdx.x & 31, ty = threadIdx.x >> 5;
    #pragma unroll
    for (int i = 0; i < 4; i++)
        tile[ty + 8*i][tx] = (bf16)ldf(in, io + (size_t)(r0 + ty + 8*i) * E_ + (c0 + tx), f32m);
    __syncthreads();
    #pragma unroll
    for (int i = 0; i < 4; i++)
        o[(size_t)(c0 + ty + 8*i) * E_ + (r0 + tx)] = tile[tx][ty + 8*i];
}

// ------- all-layer QKV bias concat: out[l][QKVN] --------------------------------
__global__ __launch_bounds__(256) void k_cat3L(const void* __restrict__ a,
    const void* __restrict__ b, const void* __restrict__ c,
    bf16* __restrict__ o, const int* __restrict__ dm)
{
    int f32m = dm[0];
    int i = blockIdx.x * 256 + threadIdx.x;   // grid covers L_*QKVN exactly
    int l = i / QKVN, j = i - l * QKVN;
    float v = (j < E_) ? ldf(a, (size_t)l * E_ + j, f32m)
            : ((j < 2*E_) ? ldf(b, (size_t)l * E_ + j - E_, f32m)
                          : ldf(c, (size_t)l * E_ + j - 2*E_, f32m));
    o[i] = (bf16)v;
}

// ---------------- reduce NZL fp32 lm_head partials -> output dtype --------------
__global__ __launch_bounds__(256) void k_cast_red(const float* __restrict__ in,
    void* __restrict__ out, const int* __restrict__ dm)
{
    const size_t S = (size_t)M_ * V_ / 4;     // f32x4 stride per z-slice
    size_t i = (size_t)blockIdx.x * 256 + threadIdx.x;
    const f32x4* p = (const f32x4*)in;
    f32x4 v = p[i];
    v += p[S + i];
    v += p[2*S + i];
    v += p[3*S + i];
    if (dm[0]) {
        ((f32x4*)out)[i] = v;
    } else {
        bf16x4 o;
        #pragma unroll
        for (int j = 0; j < 4; j++) o[j] = (bf16)v[j];
        ((bf16x4*)out)[i] = o;
    }
}

// ---------------- GEMM 128x128, single-buffered (round-4 verified 40.6 us) ------
// Flat 1-D grid, XCD-affinity decode. Double-buffering measured 74 us (64 KB LDS
// -> 2 blocks/CU residency loss, m132 lesson). At 2.25-3 blocks/CU the implicit
// wave overlap covers load latency (m131-140 regime) — leave single-buffered.
__global__ __launch_bounds__(256) void k_gemm(const bf16* __restrict__ A,
    const bf16* __restrict__ BT, const void* __restrict__ bias, size_t boff,
    void* __restrict__ outp, int M, int N, int K, int flags, const int* __restrict__ dm)
{
    int f32m = dm[0];
    __shared__ __attribute__((aligned(16))) bf16 As[128 * 64];
    __shared__ __attribute__((aligned(16))) bf16 Bs[128 * 64];
    int tid = threadIdx.x;
    int bmq, bnq;
    xcd_decode(blockIdx.x, bmq, bnq);
    int bn0 = bnq * 128, bm0 = bmq * 128;
    int wave = tid >> 6, lane = tid & 63, quad = lane >> 4, l16 = lane & 15;
    int wr = wave >> 1, wc = wave & 1;

    int st_col = 8 * ((lane & 7) ^ (lane >> 3));
    int st_row_base = wave * 32 + (lane >> 3);      // + i*8

    f32x4 acc[4][4];
    #pragma unroll
    for (int i = 0; i < 4; i++)
        #pragma unroll
        for (int j = 0; j < 4; j++)
            acc[i][j] = (f32x4){0.f, 0.f, 0.f, 0.f};

    int sw = l16 & 7;                               // read-side swizzle key
    for (int k0 = 0; k0 < K; k0 += 64) {
        #pragma unroll
        for (int i = 0; i < 4; i++) {
            int row = st_row_base + i * 8;
            const bf16* ga = A  + (size_t)(bm0 + row) * K + k0 + st_col;
            const bf16* gb = BT + (size_t)(bn0 + row) * K + k0 + st_col;
            bf16* la = As + (size_t)(wave * 256 + i * 64) * 8;
            bf16* lb = Bs + (size_t)(wave * 256 + i * 64) * 8;
            async_cp16(ga, la);
            async_cp16(gb, lb);
        }
        __syncthreads();
        #pragma unroll
        for (int ks = 0; ks < 2; ks++) {
            bf16x8 af[4], bfr[4];
            int kgs = (4*ks + quad) ^ sw;
            #pragma unroll
            for (int mi = 0; mi < 4; mi++)
                af[mi] = *(const bf16x8*)&As[(wr*64 + mi*16 + l16)*64 + kgs*8];
            #pragma unroll
            for (int ni = 0; ni < 4; ni++)
                bfr[ni] = *(const bf16x8*)&Bs[(wc*64 + ni*16 + l16)*64 + kgs*8];
            #pragma unroll
            for (int mi = 0; mi < 4; mi++)
                #pragma unroll
                for (int ni = 0; ni < 4; ni++)
                    acc[mi][ni] = __builtin_amdgcn_mfma_f32_16x16x32_bf16(af[mi], bfr[ni], acc[mi][ni], 0, 0, 0);
        }
        __syncthreads();
    }

    // epilogue: D row = base + 4*quad + reg, col = base + l16 (m89-verified)
    #pragma unroll
    for (int mi = 0; mi < 4; mi++) {
        #pragma unroll
        for (int ni = 0; ni < 4; ni++) {
            int col = bn0 + wc*64 + ni*16 + l16;
            float bv = 0.f;
            if (bias)
                bv = (flags & GF_BIAS_EXT) ? ldf(bias, boff + col, f32m)
                                           : (float)((const bf16*)bias)[col];
            #pragma unroll
            for (int r = 0; r < 4; r++) {
                int row = bm0 + wr*64 + mi*16 + quad*4 + r;
                float val = acc[mi][ni][r] + bv;
                if (flags & GF_GELU) val = gelu_f(val);
                size_t oidx = (size_t)row * N + col;
                ((bf16*)outp)[oidx] = (bf16)val;
            }
        }
    }
}

// ---------------- GEMM 128x64, single-buffered, split-K (round-4 structure) -----
// r8 post-mortem: counted-vmcnt + raw barriers REGRESSED (54->60 us; sched-pin,
// m141) and full-K at 384 blocks (1.5 blocks/CU) was the real limiter. This is
// the r4-verified config: split-K via gridDim.z -> 768 blocks (3 blocks/CU),
// 24 KB LDS, plain stage->sync->MFMA->sync loop; XCD decode kept (r7: -66% FETCH).
__global__ __launch_bounds__(256) void k_gemm64(const bf16* __restrict__ A,
    const bf16* __restrict__ BT, void* __restrict__ outp,
    int M, int N, int K, int flags, const int* __restrict__ dm)
{
    __shared__ __attribute__((aligned(16))) bf16 As[128 * 64];
    __shared__ __attribute__((aligned(16))) bf16 Bs[64 * 64];
    int tid = threadIdx.x;
    int bmq, bnq;
    xcd_decode(blockIdx.x, bmq, bnq);
    int bn0 = bnq * 64, bm0 = bmq * 128;
    int kz = blockIdx.z;
    int Ks = K / gridDim.z;
    int kbeg = kz * Ks, kend = kbeg + Ks;
    int wave = tid >> 6, lane = tid & 63, quad = lane >> 4, l16 = lane & 15;
    int wr = wave >> 1, wc = wave & 1;

    int st_col = 8 * ((lane & 7) ^ (lane >> 3));
    int lrow = lane >> 3;

    f32x4 acc[4][2];
    #pragma unroll
    for (int i = 0; i < 4; i++)
        #pragma unroll
        for (int j = 0; j < 2; j++)
            acc[i][j] = (f32x4){0.f, 0.f, 0.f, 0.f};

    int sw = l16 & 7;
    for (int k0 = kbeg; k0 < kend; k0 += 64) {
        #pragma unroll
        for (int i = 0; i < 4; i++) {       // A: 128 rows
            int row = wave * 32 + i * 8 + lrow;
            async_cp16(A + (size_t)(bm0 + row) * K + k0 + st_col,
                       As + (size_t)(wave * 32 + i * 8) * 64);
        }
        #pragma unroll
        for (int i = 0; i < 2; i++) {       // B: 64 rows
            int row = wave * 16 + i * 8 + lrow;
            async_cp16(BT + (size_t)(bn0 + row) * K + k0 + st_col,
                       Bs + (size_t)(wave * 16 + i * 8) * 64);
        }
        __syncthreads();
        #pragma unroll
        for (int ks = 0; ks < 2; ks++) {
            int kgs = (4*ks + quad) ^ sw;
            bf16x8 af[4], bfr[2];
            #pragma unroll
            for (int mi = 0; mi < 4; mi++)
                af[mi] = *(const bf16x8*)&As[(wr*64 + mi*16 + l16)*64 + kgs*8];
            #pragma unroll
            for (int ni = 0; ni < 2; ni++)
                bfr[ni] = *(const bf16x8*)&Bs[(wc*32 + ni*16 + l16)*64 + kgs*8];
            #pragma unroll
            for (int mi = 0; mi < 4; mi++)
                #pragma unroll
                for (int ni = 0; ni < 2; ni++)
                    acc[mi][ni] = __builtin_amdgcn_mfma_f32_16x16x32_bf16(af[mi], bfr[ni], acc[mi][ni], 0, 0, 0);
        }
        __syncthreads();
    }

    float* pout = (float*)outp + (size_t)kz * M * N;
    #pragma unroll
    for (int mi = 0; mi < 4; mi++) {
        #pragma unroll
        for (int ni = 0; ni < 2; ni++) {
            int col = bn0 + wc*32 + ni*16 + l16;
            #pragma unroll
            for (int r = 0; r < 4; r++) {
                int row = bm0 + wr*64 + mi*16 + quad*4 + r;
                float val = acc[mi][ni][r];
                size_t oidx = (size_t)row * N + col;
                if (flags & GF_PART) pout[oidx] = val;
                else                 ((bf16*)outp)[oidx] = (bf16)val;
            }
        }
    }
}

// ---------------- flash attention (1 strip/block, async 2-phase pipeline) --------
__device__ __forceinline__ void attn_qk_softmax2(
    const bf16x8 qf[2], f32x4 OT[4], float& m_ln, float& l_ln,
    const bf16* __restrict__ Kbuf, bf16 (*Ps)[72],
    int wave, int quad, int l16, int s0, int qt0, bool diag)
{
    f32x4 S[4];
    #pragma unroll
    for (int i = 0; i < 4; i++) S[i] = (f32x4){0.f, 0.f, 0.f, 0.f};
    #pragma unroll
    for (int ks = 0; ks < 2; ks++)
        #pragma unroll
        for (int ni = 0; ni < 4; ni++) {
            int kg = (ks*4 + quad) ^ (l16 & 7);
            bf16x8 kf = *(const bf16x8*)&Kbuf[(ni*16 + l16)*64 + kg*8];
            S[ni] = __builtin_amdgcn_mfma_f32_16x16x32_bf16(kf, qf[ks], S[ni], 0, 0, 0);
        }
    const float SC = 0.18033688011112042f;   // 0.125 * log2(e): softmax in base-2
    if (diag) {
        int qr = qt0 + wave*16 + l16;
        #pragma unroll
        for (int ni = 0; ni < 4; ni++)
            #pragma unroll
            for (int r = 0; r < 4; r++) {
                int scol = s0 + ni*16 + quad*4 + r;
                S[ni][r] = (scol > qr) ? -1e30f : S[ni][r] * SC;
            }
    } else {
        #pragma unroll
        for (int ni = 0; ni < 4; ni++)
            #pragma unroll
            for (int r = 0; r < 4; r++) S[ni][r] *= SC;
    }
    float tn[4];
    #pragma unroll
    for (int ni = 0; ni < 4; ni++)
        tn[ni] = fmaxf(fmaxf(S[ni][0], S[ni][1]), fmaxf(S[ni][2], S[ni][3]));
    float tm = fmaxf(fmaxf(tn[0], tn[1]), fmaxf(tn[2], tn[3]));
    tm = fmaxf(tm, __shfl_xor(tm, 16));
    tm = fmaxf(tm, __shfl_xor(tm, 32));
    float mnew = fmaxf(m_ln, tm);
    float alpha = exp2_hw(m_ln - mnew);
    m_ln = mnew;
    float rsum = 0.f;
    bf16x4 pk[4];
    #pragma unroll
    for (int ni = 0; ni < 4; ni++)
        #pragma unroll
        for (int r = 0; r < 4; r++) {
            float p = exp2_hw(S[ni][r] - mnew);
            rsum += p;
            pk[ni][r] = (bf16)p;
        }
    rsum += __shfl_xor(rsum, 16);
    rsum += __shfl_xor(rsum, 32);
    l_ln = l_ln * alpha + rsum;
    #pragma unroll
    for (int ni = 0; ni < 4; ni++)
        #pragma unroll
        for (int r = 0; r < 4; r++) OT[ni][r] *= alpha;        // lane-local rescale
    #pragma unroll
    for (int ni = 0; ni < 4; ni++)
        *(bf16x4*)&Ps[wave*16 + l16][ni*16 + quad*4] = pk[ni]; // wave-private rows
}

__device__ __forceinline__ void attn_pv(
    f32x4 OT[4], const bf16 (*Ps)[72], const bf16 (*Vt)[72],
    int wave, int quad, int l16)
{
    #pragma unroll
    for (int ks = 0; ks < 2; ks++) {
        bf16x8 pf = *(const bf16x8*)&Ps[wave*16 + l16][ks*32 + quad*8];
        #pragma unroll
        for (int ni = 0; ni < 4; ni++) {
            bf16x8 vf = *(const bf16x8*)&Vt[ni*16 + l16][ks*32 + quad*8];
            OT[ni] = __builtin_amdgcn_mfma_f32_16x16x32_bf16(vf, pf, OT[ni], 0, 0, 0);
        }
    }
}

__global__ __launch_bounds__(256) void k_attn(const bf16* __restrict__ qkv, bf16* __restrict__ y)
{
    int x = blockIdx.x;               // q-strip 0..15
    int qt = x * 64;
    int h = blockIdx.y, b = blockIdx.z;
    int tid = threadIdx.x, wave = tid >> 6, lane = tid & 63, quad = lane >> 4, l16 = lane & 15;

    const bf16* qb = qkv + (size_t)b * T_ * QKVN + h * 64;
    const bf16* kb = qb + E_;
    const bf16* vb = qb + 2 * E_;

    __shared__ __attribute__((aligned(16))) bf16 Kbuf[64 * 64];   // async dest, swizzled
    __shared__ __attribute__((aligned(16))) bf16 Vbuf[64 * 64];   // async dest, swizzled
    __shared__ __attribute__((aligned(16))) bf16 Vt[64][72];      // Vt[d][s]
    __shared__ __attribute__((aligned(16))) bf16 Ps[64][72];      // wave-private P rows

    // staging geometry: 8 lanes x 16B per row; XOR swizzle on SOURCE col (m173)
    int srow = tid >> 3;                               // 0..31 (+32 round 2)
    int scol = 8 * ((lane & 7) ^ (srow & 7));

    bf16x8 qf[2];
    {
        int qr = qt + wave * 16 + l16;
        #pragma unroll
        for (int ks = 0; ks < 2; ks++)
            qf[ks] = *(const bf16x8*)(qb + (size_t)qr * QKVN + ks*32 + quad*8);
    }

    f32x4 OT[4];
    #pragma unroll
    for (int i = 0; i < 4; i++) OT[i] = (f32x4){0.f,0.f,0.f,0.f};
    float m_ln = -3.0e38f, l_ln = 0.f;

    auto stage = [&](int s0) {
        #pragma unroll
        for (int i = 0; i < 2; i++) {
            int row = i * 32 + srow;
            const bf16* gk = kb + (size_t)(s0 + row) * QKVN + scol;
            const bf16* gv = vb + (size_t)(s0 + row) * QKVN + scol;
            bf16* lk = Kbuf + ((size_t)i * 32 + wave * 8) * 64;   // linear dest
            bf16* lv = Vbuf + ((size_t)i * 32 + wave * 8) * 64;
            async_cp16(gk, lk);
            async_cp16(gv, lv);
        }
    };

    stage(0);
    asm volatile("s_waitcnt vmcnt(0)" ::: "memory");
    __syncthreads();

    for (int st = 0; st <= x; st++) {
        int s0 = st * 64;
        // ---- phase 1: V transpose (Vbuf->Vt) overlapped with QK^T + softmax ----
        {
            int d = lane;
            int dg = d >> 3, de = d & 7;
            #pragma unroll
            for (int ii = 0; ii < 2; ii++) {
                int sb = wave * 2 + ii;                 // 0..7
                bf16x8 tv;
                #pragma unroll
                for (int j = 0; j < 8; j++)
                    tv[j] = Vbuf[(sb*8 + j) * 64 + ((dg ^ j) * 8) + de];
                *(bf16x8*)&Vt[d][sb * 8] = tv;
            }
        }
        attn_qk_softmax2(qf, OT, m_ln, l_ln, Kbuf, Ps, wave, quad, l16, s0, qt, st == x);
        __syncthreads();                  // Vt + Ps visible; Kbuf/Vbuf reads done
        // ---- phase 2: async stage(st+1) overlapped with PV ----
        if (st < x) stage(s0 + 64);
        attn_pv(OT, Ps, Vt, wave, quad, l16);
        asm volatile("s_waitcnt vmcnt(0)" ::: "memory");
        __syncthreads();                  // stage landed; Vt/Ps reads done
    }

    float inv = 1.f / l_ln;               // lane-local (q = w*16+l16)
    int qrow = qt + wave * 16 + l16;
    #pragma unroll
    for (int ni = 0; ni < 4; ni++) {
        bf16x4 ov;
        #pragma unroll
        for (int r = 0; r < 4; r++) ov[r] = (bf16)(OT[ni][r] * inv);
        *(bf16x4*)&y[(size_t)(b * T_ + qrow) * E_ + h*64 + ni*16 + quad*4] = ov;
    }
}

// ---------------- host-side orchestration ----------------
extern "C" void kernel_launch(void* const* d_in, const int* in_sizes, int n_in,
                              void* d_out, int out_size, void* d_ws, size_t ws_size,
                              hipStream_t stream)
{
    const void* idx     = d_in[0];
    const void* tok_emb = d_in[1];
    const void* pos_emb = d_in[2];
    const void* ln1_w   = d_in[3];
    const void* ln1_b   = d_in[4];
    const void* Wq      = d_in[5];
    const void* bq      = d_in[6];
    const void* Wk      = d_in[7];
    const void* bk      = d_in[8];
    const void* Wv      = d_in[9];
    const void* bv      = d_in[10];
    const void* Wp      = d_in[11];
    const void* bp      = d_in[12];
    const void* ln2_w   = d_in[13];
    const void* ln2_b   = d_in[14];
    const void* W1      = d_in[15];
    const void* b1      = d_in[16];
    const void* W2      = d_in[17];
    const void* b2      = d_in[18];
    const void* lnf_w   = d_in[19];
    const void* lnf_b   = d_in[20];
    const void* lm_head = d_in[21];

    char* base = (char*)d_ws;
    size_t off = 0;
    auto nxt = [&](size_t bytes) -> void* {
        void* p = base + off;
        off += (bytes + 255) & ~(size_t)255;
        return p;
    };
    int*   dm    = (int*)  nxt(256);                       // dtype-mode flags
    float* x     = (float*)nxt((size_t)M_ * E_ * 4);       // fp32 residual stream
    bf16*  h     = (bf16*) nxt((size_t)M_ * E_ * 2);       // LN output
    bf16*  qkv   = (bf16*) nxt((size_t)M_ * QKVN * 2);
    bf16*  yb    = (bf16*) nxt((size_t)M_ * E_ * 2);       // attention output
    bf16*  mbuf  = (bf16*) nxt((size_t)M_ * E4_ * 2);      // MLP intermediate
    bf16*  wqkvT = (bf16*) nxt((size_t)L_ * 3 * E_ * E_ * 2);  // all-layer W transposes
    bf16*  wpT   = (bf16*) nxt((size_t)L_ * E_ * E_ * 2);
    bf16*  w1T   = (bf16*) nxt((size_t)L_ * E_ * E4_ * 2);
    bf16*  w2T   = (bf16*) nxt((size_t)L_ * E4_ * E_ * 2);
    bf16*  lmhT  = (bf16*) nxt((size_t)V_ * E_ * 2);
    bf16*  bcat  = (bf16*) nxt((size_t)L_ * QKVN * 2);
    size_t partA = (size_t)NZP * M_ * E_ * 4;              // proj/W2 partials (25 MB)
    size_t partB = (size_t)NZL * M_ * V_ * 4;              // lm_head partials (16 MB)
    float* part  = (float*)nxt(partA > partB ? partA : partB);
    (void)ws_size; (void)in_sizes; (void)n_in; (void)out_size;

    k_probe<<<1, 256, 0, stream>>>(tok_emb, idx, dm);
    k_embed<<<M_, 256, 0, stream>>>(idx, tok_emb, pos_emb, x, dm);

    // all weight transposes + bias concat upfront (layer-static)
    k_transpose3L<<<dim3(E_/32, E_/32, 3*L_), 256, 0, stream>>>(Wq, Wk, Wv, wqkvT, dm);
    k_transposeZ<<<dim3(E_/32, E_/32, L_), 256, 0, stream>>>(Wp, 0, (size_t)E_*E_, wpT, (size_t)E_*E_, E_, E_, dm);
    k_transposeZ<<<dim3(E_/32, E4_/32, L_), 256, 0, stream>>>(W1, 0, (size_t)E_*E4_, w1T, (size_t)E_*E4_, E_, E4_, dm);
    k_transposeZ<<<dim3(E4_/32, E_/32, L_), 256, 0, stream>>>(W2, 0, (size_t)E_*E4_, w2T, (size_t)E_*E4_, E4_, E_, dm);
    k_transposeZ<<<dim3(E_/32, V_/32, 1), 256, 0, stream>>>(lm_head, 0, 0, lmhT, 0, E_, V_, dm);
    k_cat3L<<<(L_*QKVN)/256, 256, 0, stream>>>(bq, bk, bv, bcat, dm);

    // ln1 of layer 0 (subsequent ln1's are fused into the W2-partial reduce)
    k_ln<<<M_, 256, 0, stream>>>(x, ln1_w, ln1_b, 0, h, dm);

    for (int l = 0; l < L_; l++) {
        size_t voE  = (size_t)l * E_;          // element offset into [L,E]
        size_t voE4 = (size_t)l * E4_;         // element offset into [L,4E]

        // h == ln1_l(x) here; flat grids with XCD-affinity decode
        k_gemm<<<dim3((QKVN/128) * (M_/128)), 256, 0, stream>>>(h, wqkvT + (size_t)l*3*E_*E_,
            bcat + (size_t)l*QKVN, 0, qkv, M_, QKVN, E_, 0, dm);

        k_attn<<<dim3(16, H_, B_), 256, 0, stream>>>(qkv, yb);

        // proj: split-K=2 (768 blocks, 3/CU) fp32 partials; reduce fused with ln2
        k_gemm64<<<dim3((E_/64) * (M_/128), 1, NZP), 256, 0, stream>>>(yb,
            wpT + (size_t)l*E_*E_, part, M_, E_, E_, GF_PART, dm);
        k_red_ln<<<M_, 256, 0, stream>>>(x, part, bp, voE, ln2_w, ln2_b, voE, h, dm);

        k_gemm<<<dim3((E4_/128) * (M_/128)), 256, 0, stream>>>(h, w1T + (size_t)l*E_*E4_,
            b1, voE4, mbuf, M_, E4_, E_, GF_GELU | GF_BIAS_EXT, dm);

        // W2: split-K=2 partials; reduce fused with next ln1 (or lnf on last layer)
        k_gemm64<<<dim3((E_/64) * (M_/128), 1, NZP), 256, 0, stream>>>(mbuf,
            w2T + (size_t)l*E_*E4_, part, M_, E_, E4_, GF_PART, dm);
        if (l < L_ - 1)
            k_red_ln<<<M_, 256, 0, stream>>>(x, part, b2, voE, ln1_w, ln1_b, (size_t)(l+1) * E_, h, dm);
        else
            k_red_ln<<<M_, 256, 0, stream>>>(x, part, b2, voE, lnf_w, lnf_b, 0, h, dm);
    }

    // lm_head: split-K=4 (flat 128 blocks x z=4) partials -> fused reduce+cast
    k_gemm64<<<dim3((V_/64) * (M_/128), 1, NZL), 256, 0, stream>>>(h, lmhT,
        part, M_, V_, E_, GF_PART, dm);
    k_cast_red<<<(M_*V_)/1024, 256, 0, stream>>>(part, d_out, dm);
}